// Round 7
// baseline (371.906 us; speedup 1.0000x reference)
//
#include <hip/hip_runtime.h>
#include <math.h>

#define EDIM 100
#define KP   128          // padded K
#define NF   4000
#define NN   4000
#define NB   8
#define NP   4096         // padded N and F
#define BN   128          // n-rows per main block
#define FCH  32           // f-chunks (grid.y); each block covers 128 f

#define CVT_BLOCKS 1536   // 3 matrices * (NP*KP/4)/256
#define E2_BLOCKS  16
#define P_BLOCKS   128    // NP/32

typedef __attribute__((ext_vector_type(8))) short short8;
typedef __attribute__((ext_vector_type(4))) float floatx4;

// Static device scratch.
__device__ __align__(16) unsigned short g_A [NP * KP];   // ent  bf16
__device__ __align__(16) unsigned short g_B1[NP * KP];   // fa1  bf16
__device__ __align__(16) unsigned short g_B2[NP * KP];   // fa2  bf16
__device__ __align__(16) float g_P[2 * NB * NP];         // [g][b][f], +INF pad
__device__ float g_e2[NN];
__device__ float g_part[2 * NB * FCH * NP];              // [g][b][fch][n]

__device__ __forceinline__ unsigned short f2bf(float x) {
    union { float f; unsigned int u; } v; v.f = x;
    unsigned int r = v.u + 0x7FFFu + ((v.u >> 16) & 1u);  // RNE
    return (unsigned short)(r >> 16);
}

// Fused prep: convert (bf16 pad), e2, P — partitioned by blockIdx.x.
__global__ void __launch_bounds__(256) prep(const float* __restrict__ rel,
                                            const float* __restrict__ arg1,
                                            const float* __restrict__ arg2,
                                            const float* __restrict__ frel,
                                            const float* __restrict__ fa1,
                                            const float* __restrict__ fa2,
                                            const float* __restrict__ ent) {
    __shared__ float lf[3][32][104];   // fact rows (frel,fa1,fa2), padded
    __shared__ float lq[3][8][104];    // rel,arg1,arg2 rows
    const int bid = blockIdx.x;
    const int t = threadIdx.x;

    if (bid < CVT_BLOCKS) {
        // ---- convert fp32 [4000][100] -> bf16 [4096][128] zero-pad ----
        const int mat = bid >> 9;                  // /512
        const int g4 = ((bid & 511) * 256 + t);    // float4-chunk id
        const int rw = g4 >> 5;                    // row
        const int ck = g4 & 31;                    // chunk-of-row
        const float* src = (mat == 0) ? ent : (mat == 1) ? fa1 : fa2;
        unsigned short* dst = (mat == 0) ? g_A : (mat == 1) ? g_B1 : g_B2;
        float4 v = {0.f, 0.f, 0.f, 0.f};
        if (rw < NF && ck < 25) v = ((const float4*)src)[rw * 25 + ck];
        ushort4 o;
        o.x = f2bf(v.x); o.y = f2bf(v.y); o.z = f2bf(v.z); o.w = f2bf(v.w);
        ((ushort4*)dst)[g4] = o;
        return;
    }
    if (bid < CVT_BLOCKS + E2_BLOCKS) {
        int n = (bid - CVT_BLOCKS) * 256 + t;
        if (n < NN) {
            const float4* ep = (const float4*)(ent + n * EDIM);
            float s = 0.f;
            #pragma unroll
            for (int i = 0; i < 25; i++) {
                float4 v = ep[i];
                s += v.x * v.x + v.y * v.y + v.z * v.z + v.w * v.w;
            }
            g_e2[n] = s;
        }
        return;
    }
    // ---- P part: 32 f's per block ----
    const int fb = bid - CVT_BLOCKS - E2_BLOCKS;   // 0..127
    for (int i = t; i < 2400; i += 256) {
        int mat = i / 800, rem = i % 800;
        int rr = rem / 25, kc = rem % 25;
        int gf = fb * 32 + rr;
        const float* src = (mat == 0) ? frel : (mat == 1) ? fa1 : fa2;
        float4 v = {0.f, 0.f, 0.f, 0.f};
        if (gf < NF) v = ((const float4*)src)[gf * 25 + kc];
        *(float4*)&lf[mat][rr][kc * 4] = v;
    }
    for (int i = t; i < 600; i += 256) {
        int mat = i / 200, rem = i % 200;
        int rr = rem / 25, kc = rem % 25;
        const float* src = (mat == 0) ? rel : (mat == 1) ? arg1 : arg2;
        *(float4*)&lq[mat][rr][kc * 4] = ((const float4*)src)[rr * 25 + kc];
    }
    __syncthreads();
    const int fl = t >> 3, b = t & 7;
    const int f = fb * 32 + fl;
    float nf = 0.f, dr = 0.f, d1 = 0.f, d2 = 0.f, qr = 0.f, q1 = 0.f, q2 = 0.f;
    for (int kc = 0; kc < 25; kc++) {
        float4 vr = *(const float4*)&lf[0][fl][kc * 4];
        float4 v1 = *(const float4*)&lf[1][fl][kc * 4];
        float4 v2 = *(const float4*)&lf[2][fl][kc * 4];
        float4 rb = *(const float4*)&lq[0][b][kc * 4];
        float4 a1 = *(const float4*)&lq[1][b][kc * 4];
        float4 a2 = *(const float4*)&lq[2][b][kc * 4];
        nf += vr.x*vr.x + vr.y*vr.y + vr.z*vr.z + vr.w*vr.w
            + v1.x*v1.x + v1.y*v1.y + v1.z*v1.z + v1.w*v1.w
            + v2.x*v2.x + v2.y*v2.y + v2.z*v2.z + v2.w*v2.w;
        dr += vr.x*rb.x + vr.y*rb.y + vr.z*rb.z + vr.w*rb.w;
        d1 += v1.x*a1.x + v1.y*a1.y + v1.z*a1.z + v1.w*a1.w;
        d2 += v2.x*a2.x + v2.y*a2.y + v2.z*a2.z + v2.w*a2.w;
        qr += rb.x*rb.x + rb.y*rb.y + rb.z*rb.z + rb.w*rb.w;
        q1 += a1.x*a1.x + a1.y*a1.y + a1.z*a1.z + a1.w*a1.w;
        q2 += a2.x*a2.x + a2.y*a2.y + a2.z*a2.z + a2.w*a2.w;
    }
    float psp = nf + qr + q1 - 2.f * (dr + d1);
    float ppo = nf + qr + q2 - 2.f * (dr + d2);
    if (f >= NF) { psp = __builtin_inff(); ppo = __builtin_inff(); }
    g_P[(0 * NB + b) * NP + f] = psp;
    g_P[(1 * NB + b) * NP + f] = ppo;
}

// Main: f-as-row MFMA orientation -> fold is pure in-register fma+min.
// Block: 128 n x 128 f. Wave: 32 n (nt=2). f-iter: 64 f (ft=4), K=128 unrolled.
// C layout (m74/m89): row = q*4+r -> f (consecutive!), col = c -> n.
// No LDS at all. P[g][b][f] float4 load covers a lane's 4 f's exactly.
__global__ void __launch_bounds__(256, 2) main_kernel() {
    const int t = threadIdx.x;
    const int lane = t & 63;
    const int c = lane & 15;
    const int q = lane >> 4;
    const int w = t >> 6;
    const int nw = blockIdx.x * BN + w * 32;    // this wave's n-base
    const int f0c = blockIdx.y * 128;           // this block's f-base

    const short8* gA8  = (const short8*)g_A;    // 16 chunks (16B) per row
    const short8* gB18 = (const short8*)g_B1;
    const short8* gB28 = (const short8*)g_B2;
    const float4* gP4  = (const float4*)g_P;

    float m[2][8][2];                           // [g][b][nt] running min
    #pragma unroll
    for (int g = 0; g < 2; g++)
        #pragma unroll
        for (int b = 0; b < NB; b++) {
            m[g][b][0] = __builtin_inff();
            m[g][b][1] = __builtin_inff();
        }

    const int arow0 = (nw + c) * 16;            // ent rows (n-side)
    const int arow1 = (nw + 16 + c) * 16;

    #pragma unroll
    for (int it = 0; it < 2; it++) {
        const int f0 = f0c + it * 64;

        floatx4 acc[2][4][2];                   // [g][ft][nt]
        #pragma unroll
        for (int g = 0; g < 2; g++)
            #pragma unroll
            for (int ft = 0; ft < 4; ft++) {
                acc[g][ft][0] = (floatx4){0.f, 0.f, 0.f, 0.f};
                acc[g][ft][1] = (floatx4){0.f, 0.f, 0.f, 0.f};
            }

        #pragma unroll
        for (int s = 0; s < 4; s++) {           // K-steps of 32
            const int ch = s * 4 + q;
            short8 e0 = gA8[arow0 + ch];
            short8 e1 = gA8[arow1 + ch];
            #pragma unroll
            for (int ft = 0; ft < 4; ft++) {
                const int frow = (f0 + ft * 16 + c) * 16 + ch;
                short8 f1 = gB18[frow];
                short8 f2 = gB28[frow];
                // g=0 (sp) uses fa2; g=1 (po) uses fa1. fact = row operand.
                acc[0][ft][0] = __builtin_amdgcn_mfma_f32_16x16x32_bf16(f2, e0, acc[0][ft][0], 0, 0, 0);
                acc[0][ft][1] = __builtin_amdgcn_mfma_f32_16x16x32_bf16(f2, e1, acc[0][ft][1], 0, 0, 0);
                acc[1][ft][0] = __builtin_amdgcn_mfma_f32_16x16x32_bf16(f1, e0, acc[1][ft][0], 0, 0, 0);
                acc[1][ft][1] = __builtin_amdgcn_mfma_f32_16x16x32_bf16(f1, e1, acc[1][ft][1], 0, 0, 0);
            }
        }

        // ---- in-register fold: lane's acc rows are f = f0+ft*16+q*4+r ----
        #pragma unroll
        for (int g = 0; g < 2; g++)
            #pragma unroll
            for (int ft = 0; ft < 4; ft++) {
                const int pidx = (g * NB) * (NP / 4) + ((f0 + ft * 16) >> 2) + q;
                #pragma unroll
                for (int b = 0; b < NB; b++) {
                    float4 p = gP4[pidx + b * (NP / 4)];
                    #pragma unroll
                    for (int nt = 0; nt < 2; nt++) {
                        floatx4 a = acc[g][ft][nt];
                        float v = fminf(fminf(fmaf(-2.f, a[0], p.x), fmaf(-2.f, a[1], p.y)),
                                        fminf(fmaf(-2.f, a[2], p.z), fmaf(-2.f, a[3], p.w)));
                        m[g][b][nt] = fminf(m[g][b][nt], v);
                    }
                }
            }
    }

    // ---- cross-lane min over q-groups (f mod 16 coverage), then store ----
    #pragma unroll
    for (int g = 0; g < 2; g++)
        #pragma unroll
        for (int b = 0; b < NB; b++)
            #pragma unroll
            for (int nt = 0; nt < 2; nt++) {
                float v = m[g][b][nt];
                v = fminf(v, __shfl_xor(v, 16));
                v = fminf(v, __shfl_xor(v, 32));
                if (q == 0)
                    g_part[((g * NB + b) * FCH + blockIdx.y) * NP + nw + nt * 16 + c] = v;
            }
}

__global__ void finalize(float* __restrict__ out) {
    int idx = blockIdx.x * 256 + threadIdx.x;   // out layout (g*NB+b)*NN+n
    if (idx >= 2 * NB * NN) return;
    int sb = idx / NN;
    int n = idx % NN;
    float m = __builtin_inff();
    #pragma unroll 8
    for (int j = 0; j < FCH; j++) m = fminf(m, g_part[(sb * FCH + j) * NP + n]);
    float d2 = fmaxf(m + g_e2[n], 0.f);
    out[idx] = expf(-0.5f * d2);
}

extern "C" void kernel_launch(void* const* d_in, const int* in_sizes, int n_in,
                              void* d_out, int out_size, void* d_ws, size_t ws_size,
                              hipStream_t stream) {
    const float* rel  = (const float*)d_in[0];
    const float* arg1 = (const float*)d_in[1];
    const float* arg2 = (const float*)d_in[2];
    const float* frel = (const float*)d_in[3];
    const float* fa1  = (const float*)d_in[4];
    const float* fa2  = (const float*)d_in[5];
    const float* ent  = (const float*)d_in[6];
    float* out = (float*)d_out;

    prep<<<CVT_BLOCKS + E2_BLOCKS + P_BLOCKS, 256, 0, stream>>>(rel, arg1, arg2, frel, fa1, fa2, ent);
    main_kernel<<<dim3(NP / BN, FCH), 256, 0, stream>>>();
    finalize<<<(2 * NB * NN + 255) / 256, 256, 0, stream>>>(out);
}

// Round 8
// 357.718 us; speedup vs baseline: 1.0397x; 1.0397x over previous
//
#include <hip/hip_runtime.h>
#include <math.h>

#define EDIM 100
#define KP   128          // padded K
#define NF   4000
#define NN   4000
#define NB   8
#define NP   4096         // padded N and F
#define BN   128          // n-rows per main block
#define FCH  32           // f-chunks (grid.y); each block covers 128 f

#define CVT_BLOCKS 1536   // 3 matrices * (NP*KP/4)/256
#define E2_BLOCKS  16
#define P_BLOCKS   128    // NP/32

typedef __attribute__((ext_vector_type(8))) short short8;
typedef __attribute__((ext_vector_type(4))) float floatx4;

// Static device scratch.
__device__ __align__(16) unsigned short g_A [NP * KP];   // ent  bf16
__device__ __align__(16) unsigned short g_B1[NP * KP];   // fa1  bf16
__device__ __align__(16) unsigned short g_B2[NP * KP];   // fa2  bf16
__device__ __align__(16) float g_P[2 * NB * NP];         // [g][b][f], +INF pad
__device__ float g_e2[NN];
__device__ float g_part[2 * NB * FCH * NP];              // [g][b][fch][n]

__device__ __forceinline__ unsigned short f2bf(float x) {
    union { float f; unsigned int u; } v; v.f = x;
    unsigned int r = v.u + 0x7FFFu + ((v.u >> 16) & 1u);  // RNE
    return (unsigned short)(r >> 16);
}

// Fused prep: convert (bf16 pad), e2, P — partitioned by blockIdx.x.
__global__ void __launch_bounds__(256) prep(const float* __restrict__ rel,
                                            const float* __restrict__ arg1,
                                            const float* __restrict__ arg2,
                                            const float* __restrict__ frel,
                                            const float* __restrict__ fa1,
                                            const float* __restrict__ fa2,
                                            const float* __restrict__ ent) {
    __shared__ float lf[3][32][104];   // fact rows (frel,fa1,fa2), padded
    __shared__ float lq[3][8][104];    // rel,arg1,arg2 rows
    const int bid = blockIdx.x;
    const int t = threadIdx.x;

    if (bid < CVT_BLOCKS) {
        // ---- convert fp32 [4000][100] -> bf16 [4096][128] zero-pad ----
        const int mat = bid >> 9;                  // /512
        const int g4 = ((bid & 511) * 256 + t);    // float4-chunk id
        const int rw = g4 >> 5;                    // row
        const int ck = g4 & 31;                    // chunk-of-row
        const float* src = (mat == 0) ? ent : (mat == 1) ? fa1 : fa2;
        unsigned short* dst = (mat == 0) ? g_A : (mat == 1) ? g_B1 : g_B2;
        float4 v = {0.f, 0.f, 0.f, 0.f};
        if (rw < NF && ck < 25) v = ((const float4*)src)[rw * 25 + ck];
        ushort4 o;
        o.x = f2bf(v.x); o.y = f2bf(v.y); o.z = f2bf(v.z); o.w = f2bf(v.w);
        ((ushort4*)dst)[g4] = o;
        return;
    }
    if (bid < CVT_BLOCKS + E2_BLOCKS) {
        int n = (bid - CVT_BLOCKS) * 256 + t;
        if (n < NN) {
            const float4* ep = (const float4*)(ent + n * EDIM);
            float s = 0.f;
            #pragma unroll
            for (int i = 0; i < 25; i++) {
                float4 v = ep[i];
                s += v.x * v.x + v.y * v.y + v.z * v.z + v.w * v.w;
            }
            g_e2[n] = s;
        }
        return;
    }
    // ---- P part: 32 f's per block ----
    const int fb = bid - CVT_BLOCKS - E2_BLOCKS;   // 0..127
    for (int i = t; i < 2400; i += 256) {
        int mat = i / 800, rem = i % 800;
        int rr = rem / 25, kc = rem % 25;
        int gf = fb * 32 + rr;
        const float* src = (mat == 0) ? frel : (mat == 1) ? fa1 : fa2;
        float4 v = {0.f, 0.f, 0.f, 0.f};
        if (gf < NF) v = ((const float4*)src)[gf * 25 + kc];
        *(float4*)&lf[mat][rr][kc * 4] = v;
    }
    for (int i = t; i < 600; i += 256) {
        int mat = i / 200, rem = i % 200;
        int rr = rem / 25, kc = rem % 25;
        const float* src = (mat == 0) ? rel : (mat == 1) ? arg1 : arg2;
        *(float4*)&lq[mat][rr][kc * 4] = ((const float4*)src)[rr * 25 + kc];
    }
    __syncthreads();
    const int fl = t >> 3, b = t & 7;
    const int f = fb * 32 + fl;
    float nf = 0.f, dr = 0.f, d1 = 0.f, d2 = 0.f, qr = 0.f, q1 = 0.f, q2 = 0.f;
    for (int kc = 0; kc < 25; kc++) {
        float4 vr = *(const float4*)&lf[0][fl][kc * 4];
        float4 v1 = *(const float4*)&lf[1][fl][kc * 4];
        float4 v2 = *(const float4*)&lf[2][fl][kc * 4];
        float4 rb = *(const float4*)&lq[0][b][kc * 4];
        float4 a1 = *(const float4*)&lq[1][b][kc * 4];
        float4 a2 = *(const float4*)&lq[2][b][kc * 4];
        nf += vr.x*vr.x + vr.y*vr.y + vr.z*vr.z + vr.w*vr.w
            + v1.x*v1.x + v1.y*v1.y + v1.z*v1.z + v1.w*v1.w
            + v2.x*v2.x + v2.y*v2.y + v2.z*v2.z + v2.w*v2.w;
        dr += vr.x*rb.x + vr.y*rb.y + vr.z*rb.z + vr.w*rb.w;
        d1 += v1.x*a1.x + v1.y*a1.y + v1.z*a1.z + v1.w*a1.w;
        d2 += v2.x*a2.x + v2.y*a2.y + v2.z*a2.z + v2.w*a2.w;
        qr += rb.x*rb.x + rb.y*rb.y + rb.z*rb.z + rb.w*rb.w;
        q1 += a1.x*a1.x + a1.y*a1.y + a1.z*a1.z + a1.w*a1.w;
        q2 += a2.x*a2.x + a2.y*a2.y + a2.z*a2.z + a2.w*a2.w;
    }
    float psp = nf + qr + q1 - 2.f * (dr + d1);
    float ppo = nf + qr + q2 - 2.f * (dr + d2);
    if (f >= NF) { psp = __builtin_inff(); ppo = __builtin_inff(); }
    g_P[(0 * NB + b) * NP + f] = psp;
    g_P[(1 * NB + b) * NP + f] = ppo;
}

// Main: f-as-row MFMA; fold in registers; g sequential to halve live state.
// Block: 128 n x 128 f. Wave: 32 n (nt=2). e-frags preloaded once (32 VGPRs).
// C layout (m74/m89): row = q*4+r -> f (consecutive), col = c -> n.
__global__ void __launch_bounds__(256, 2) main_kernel() {
    const int t = threadIdx.x;
    const int lane = t & 63;
    const int c = lane & 15;
    const int q = lane >> 4;
    const int w = t >> 6;
    const int nw = blockIdx.x * BN + w * 32;    // this wave's n-base
    const int f0c = blockIdx.y * 128;           // this block's f-base

    const short8* gA8  = (const short8*)g_A;    // 16 chunks (16B) per row
    const short8* gB18 = (const short8*)g_B1;
    const short8* gB28 = (const short8*)g_B2;
    const float4* gP4  = (const float4*)g_P;

    // ---- preload ent fragments for this wave: e[nt][s], reused 4x ----
    short8 e[2][4];
    #pragma unroll
    for (int nt = 0; nt < 2; nt++)
        #pragma unroll
        for (int s = 0; s < 4; s++)
            e[nt][s] = gA8[(nw + nt * 16 + c) * 16 + s * 4 + q];

    float m[2][NB][2];                          // [g][b][nt] running min
    #pragma unroll
    for (int g = 0; g < 2; g++)
        #pragma unroll
        for (int b = 0; b < NB; b++) {
            m[g][b][0] = __builtin_inff();
            m[g][b][1] = __builtin_inff();
        }

    #pragma unroll
    for (int it = 0; it < 2; it++) {            // f half-tile
        const int f0 = f0c + it * 64;
        #pragma unroll
        for (int g = 0; g < 2; g++) {           // g=0 (sp) uses fa2; g=1 uses fa1
            const short8* gF = (g == 0) ? gB28 : gB18;

            floatx4 acc[4][2];                  // [ft][nt]
            #pragma unroll
            for (int ft = 0; ft < 4; ft++) {
                acc[ft][0] = (floatx4){0.f, 0.f, 0.f, 0.f};
                acc[ft][1] = (floatx4){0.f, 0.f, 0.f, 0.f};
            }

            #pragma unroll
            for (int s = 0; s < 4; s++) {       // K-steps of 32
                const int ch = s * 4 + q;
                #pragma unroll
                for (int ft = 0; ft < 4; ft++) {
                    short8 fv = gF[(f0 + ft * 16 + c) * 16 + ch];
                    acc[ft][0] = __builtin_amdgcn_mfma_f32_16x16x32_bf16(fv, e[0][s], acc[ft][0], 0, 0, 0);
                    acc[ft][1] = __builtin_amdgcn_mfma_f32_16x16x32_bf16(fv, e[1][s], acc[ft][1], 0, 0, 0);
                }
            }

            // ---- fold: lane's acc rows are f = f0+ft*16+q*4+r ----
            #pragma unroll
            for (int ft = 0; ft < 4; ft++) {
                const int pidx = ((g * NB) * NP + f0 + ft * 16) / 4 + q;
                #pragma unroll
                for (int b = 0; b < NB; b++) {
                    float4 p = gP4[pidx + b * (NP / 4)];
                    #pragma unroll
                    for (int nt = 0; nt < 2; nt++) {
                        floatx4 a = acc[ft][nt];
                        float v = fminf(fminf(fmaf(-2.f, a[0], p.x), fmaf(-2.f, a[1], p.y)),
                                        fminf(fmaf(-2.f, a[2], p.z), fmaf(-2.f, a[3], p.w)));
                        m[g][b][nt] = fminf(m[g][b][nt], v);
                    }
                }
            }
        }
    }

    // ---- cross-lane min over q-groups, then store (q==0 lanes) ----
    #pragma unroll
    for (int g = 0; g < 2; g++)
        #pragma unroll
        for (int b = 0; b < NB; b++)
            #pragma unroll
            for (int nt = 0; nt < 2; nt++) {
                float v = m[g][b][nt];
                v = fminf(v, __shfl_xor(v, 16));
                v = fminf(v, __shfl_xor(v, 32));
                if (q == 0)
                    g_part[((g * NB + b) * FCH + blockIdx.y) * NP + nw + nt * 16 + c] = v;
            }
}

__global__ void finalize(float* __restrict__ out) {
    int idx = blockIdx.x * 256 + threadIdx.x;   // out layout (g*NB+b)*NN+n
    if (idx >= 2 * NB * NN) return;
    int sb = idx / NN;
    int n = idx % NN;
    float m = __builtin_inff();
    #pragma unroll 8
    for (int j = 0; j < FCH; j++) m = fminf(m, g_part[(sb * FCH + j) * NP + n]);
    float d2 = fmaxf(m + g_e2[n], 0.f);
    out[idx] = expf(-0.5f * d2);
}

extern "C" void kernel_launch(void* const* d_in, const int* in_sizes, int n_in,
                              void* d_out, int out_size, void* d_ws, size_t ws_size,
                              hipStream_t stream) {
    const float* rel  = (const float*)d_in[0];
    const float* arg1 = (const float*)d_in[1];
    const float* arg2 = (const float*)d_in[2];
    const float* frel = (const float*)d_in[3];
    const float* fa1  = (const float*)d_in[4];
    const float* fa2  = (const float*)d_in[5];
    const float* ent  = (const float*)d_in[6];
    float* out = (float*)d_out;

    prep<<<CVT_BLOCKS + E2_BLOCKS + P_BLOCKS, 256, 0, stream>>>(rel, arg1, arg2, frel, fa1, fa2, ent);
    main_kernel<<<dim3(NP / BN, FCH), 256, 0, stream>>>();
    finalize<<<(2 * NB * NN + 255) / 256, 256, 0, stream>>>(out);
}

// Round 9
// 244.563 us; speedup vs baseline: 1.5207x; 1.4627x over previous
//
#include <hip/hip_runtime.h>
#include <math.h>

#define EDIM 100
#define KP   128          // padded K
#define NF   4000
#define NN   4000
#define NB   8
#define NP   4096         // padded N and F
#define BN   128          // n-rows per main block (4 waves x 32)
#define BF   64           // f-cols per main block
#define NFB  (NP / BF)    // 64 f-blocks

#define CVT_BLOCKS 1536   // 3 matrices * (NP*KP/4)/256
#define E2_BLOCKS  16
#define P_BLOCKS   128    // NP/32

typedef __attribute__((ext_vector_type(8))) short short8;
typedef __attribute__((ext_vector_type(4))) float floatx4;

// Static device scratch.
__device__ __align__(16) unsigned short g_A [NP * KP];   // ent  bf16
__device__ __align__(16) unsigned short g_B1[NP * KP];   // fa1  bf16
__device__ __align__(16) unsigned short g_B2[NP * KP];   // fa2  bf16
__device__ __align__(16) float g_P[2 * NB * NP];         // [g][b][f], +INF pad
__device__ float g_e2[NN];
__device__ float g_part[2 * NB * NFB * NP];              // [g][b][fblk][n]

__device__ __forceinline__ unsigned short f2bf(float x) {
    union { float f; unsigned int u; } v; v.f = x;
    unsigned int r = v.u + 0x7FFFu + ((v.u >> 16) & 1u);  // RNE
    return (unsigned short)(r >> 16);
}

// Fused prep: convert (bf16 pad), e2, P — partitioned by blockIdx.x.
__global__ void __launch_bounds__(256) prep(const float* __restrict__ rel,
                                            const float* __restrict__ arg1,
                                            const float* __restrict__ arg2,
                                            const float* __restrict__ frel,
                                            const float* __restrict__ fa1,
                                            const float* __restrict__ fa2,
                                            const float* __restrict__ ent) {
    __shared__ float lf[3][32][104];   // fact rows (frel,fa1,fa2), padded
    __shared__ float lq[3][8][104];    // rel,arg1,arg2 rows
    const int bid = blockIdx.x;
    const int t = threadIdx.x;

    if (bid < CVT_BLOCKS) {
        // ---- convert fp32 [4000][100] -> bf16 [4096][128] zero-pad ----
        const int mat = bid >> 9;                  // /512
        const int g4 = ((bid & 511) * 256 + t);    // float4-chunk id
        const int rw = g4 >> 5;                    // row
        const int ck = g4 & 31;                    // chunk-of-row
        const float* src = (mat == 0) ? ent : (mat == 1) ? fa1 : fa2;
        unsigned short* dst = (mat == 0) ? g_A : (mat == 1) ? g_B1 : g_B2;
        float4 v = {0.f, 0.f, 0.f, 0.f};
        if (rw < NF && ck < 25) v = ((const float4*)src)[rw * 25 + ck];
        ushort4 o;
        o.x = f2bf(v.x); o.y = f2bf(v.y); o.z = f2bf(v.z); o.w = f2bf(v.w);
        ((ushort4*)dst)[g4] = o;
        return;
    }
    if (bid < CVT_BLOCKS + E2_BLOCKS) {
        int n = (bid - CVT_BLOCKS) * 256 + t;
        if (n < NN) {
            const float4* ep = (const float4*)(ent + n * EDIM);
            float s = 0.f;
            #pragma unroll
            for (int i = 0; i < 25; i++) {
                float4 v = ep[i];
                s += v.x * v.x + v.y * v.y + v.z * v.z + v.w * v.w;
            }
            g_e2[n] = s;
        }
        return;
    }
    // ---- P part: 32 f's per block ----
    const int fb = bid - CVT_BLOCKS - E2_BLOCKS;   // 0..127
    for (int i = t; i < 2400; i += 256) {
        int mat = i / 800, rem = i % 800;
        int rr = rem / 25, kc = rem % 25;
        int gf = fb * 32 + rr;
        const float* src = (mat == 0) ? frel : (mat == 1) ? fa1 : fa2;
        float4 v = {0.f, 0.f, 0.f, 0.f};
        if (gf < NF) v = ((const float4*)src)[gf * 25 + kc];
        *(float4*)&lf[mat][rr][kc * 4] = v;
    }
    for (int i = t; i < 600; i += 256) {
        int mat = i / 200, rem = i % 200;
        int rr = rem / 25, kc = rem % 25;
        const float* src = (mat == 0) ? rel : (mat == 1) ? arg1 : arg2;
        *(float4*)&lq[mat][rr][kc * 4] = ((const float4*)src)[rr * 25 + kc];
    }
    __syncthreads();
    const int fl = t >> 3, b = t & 7;
    const int f = fb * 32 + fl;
    float nf = 0.f, dr = 0.f, d1 = 0.f, d2 = 0.f, qr = 0.f, q1 = 0.f, q2 = 0.f;
    for (int kc = 0; kc < 25; kc++) {
        float4 vr = *(const float4*)&lf[0][fl][kc * 4];
        float4 v1 = *(const float4*)&lf[1][fl][kc * 4];
        float4 v2 = *(const float4*)&lf[2][fl][kc * 4];
        float4 rb = *(const float4*)&lq[0][b][kc * 4];
        float4 a1 = *(const float4*)&lq[1][b][kc * 4];
        float4 a2 = *(const float4*)&lq[2][b][kc * 4];
        nf += vr.x*vr.x + vr.y*vr.y + vr.z*vr.z + vr.w*vr.w
            + v1.x*v1.x + v1.y*v1.y + v1.z*v1.z + v1.w*v1.w
            + v2.x*v2.x + v2.y*v2.y + v2.z*v2.z + v2.w*v2.w;
        dr += vr.x*rb.x + vr.y*rb.y + vr.z*rb.z + vr.w*rb.w;
        d1 += v1.x*a1.x + v1.y*a1.y + v1.z*a1.z + v1.w*a1.w;
        d2 += v2.x*a2.x + v2.y*a2.y + v2.z*a2.z + v2.w*a2.w;
        qr += rb.x*rb.x + rb.y*rb.y + rb.z*rb.z + rb.w*rb.w;
        q1 += a1.x*a1.x + a1.y*a1.y + a1.z*a1.z + a1.w*a1.w;
        q2 += a2.x*a2.x + a2.y*a2.y + a2.z*a2.z + a2.w*a2.w;
    }
    float psp = nf + qr + q1 - 2.f * (dr + d1);
    float ppo = nf + qr + q2 - 2.f * (dr + d2);
    if (f >= NF) { psp = __builtin_inff(); ppo = __builtin_inff(); }
    g_P[(0 * NB + b) * NP + f] = psp;
    g_P[(1 * NB + b) * NP + f] = ppo;
}

// Main: f-as-row MFMA, in-register fold. B1/B2/P staged in LDS (36 KB);
// A (ent) fragments preloaded once into registers from global.
// Block: 128 n x 64 f, K=128. Wave: 32 n (nt=2), 4 f-tiles of 16 (ft).
// Layouts (m89/m74): A-op m=lane&15, k=quad*8+j; C/D row(q*4+r)=m-dim(f!),
// col(c)=n-dim -> lane's 4 acc values are 4 CONSECUTIVE f's.
__global__ void __launch_bounds__(256, 3) main_kernel() {
    __shared__ float4 lB14[BF * 16];     // 16 KB, XOR-swizzled chunks
    __shared__ float4 lB24[BF * 16];     // 16 KB
    __shared__ float  lP[2 * NB * BF];   //  4 KB  [g][b][f_local]

    const int t = threadIdx.x;
    const int lane = t & 63;
    const int c = lane & 15;
    const int q = lane >> 4;
    const int w = t >> 6;
    const int nw = blockIdx.x * BN + w * 32;    // wave's n-base
    const int fblk = blockIdx.y;
    const int f0 = fblk * BF;

    const short8* gA8 = (const short8*)g_A;     // 16 chunks/row

    // ---- preload ent fragments (safe: issued once, before barrier) ----
    short8 e[2][4];                             // [nt][s] = 32 VGPRs
    #pragma unroll
    for (int nt = 0; nt < 2; nt++)
        #pragma unroll
        for (int s = 0; s < 4; s++)
            e[nt][s] = gA8[(nw + nt * 16 + c) * 16 + s * 4 + q];

    // ---- stage B1/B2 (XOR chunk swizzle, proven conflict-free) + P ----
    const float4* gB14 = (const float4*)g_B1;
    const float4* gB24 = (const float4*)g_B2;
    #pragma unroll
    for (int i = 0; i < 4; i++) {               // 64 rows * 16 chunks / 256 thr
        int gc = i * 256 + t;
        int rw = gc >> 4, ch = gc & 15;
        int sl = rw * 16 + (ch ^ (rw & 15));
        lB14[sl] = gB14[f0 * 16 + gc];
        lB24[sl] = gB24[f0 * 16 + gc];
    }
    {                                           // P: 16 (g,b) x 16 float4
        int sb = t >> 4, fc = t & 15;
        ((float4*)lP)[t] = ((const float4*)g_P)[sb * (NP / 4) + (f0 >> 2) + fc];
    }
    __syncthreads();

    float m[2][NB][2];                          // [g][b][nt] running min
    #pragma unroll
    for (int g = 0; g < 2; g++)
        #pragma unroll
        for (int b = 0; b < NB; b++) {
            m[g][b][0] = __builtin_inff();
            m[g][b][1] = __builtin_inff();
        }

    const float4* lPf4 = (const float4*)lP;

    #pragma unroll
    for (int g = 0; g < 2; g++) {               // g=0 (sp) uses fa2; g=1 uses fa1
        const short8* pB = (const short8*)((g == 0) ? lB24 : lB14);

        floatx4 acc[4][2];                      // [ft][nt] -> AGPRs
        #pragma unroll
        for (int ft = 0; ft < 4; ft++) {
            acc[ft][0] = (floatx4){0.f, 0.f, 0.f, 0.f};
            acc[ft][1] = (floatx4){0.f, 0.f, 0.f, 0.f};
        }

        #pragma unroll
        for (int s = 0; s < 4; s++) {           // K-steps of 32
            const int base = s * 4 + q;
            #pragma unroll
            for (int ft = 0; ft < 4; ft++) {
                short8 fv = pB[(ft * 16 + c) * 16 + (base ^ c)];  // fact row = m-op
                acc[ft][0] = __builtin_amdgcn_mfma_f32_16x16x32_bf16(fv, e[0][s], acc[ft][0], 0, 0, 0);
                acc[ft][1] = __builtin_amdgcn_mfma_f32_16x16x32_bf16(fv, e[1][s], acc[ft][1], 0, 0, 0);
            }
        }

        // ---- fold: lane's acc[ft][nt][r] = G[f0+ft*16+q*4+r][nw+nt*16+c] ----
        #pragma unroll
        for (int ft = 0; ft < 4; ft++)
            #pragma unroll
            for (int b = 0; b < NB; b++) {
                float4 p = lPf4[(g * NB + b) * 16 + ft * 4 + q];  // broadcast read
                #pragma unroll
                for (int nt = 0; nt < 2; nt++) {
                    floatx4 a = acc[ft][nt];
                    float v = fminf(fminf(fmaf(-2.f, a[0], p.x), fmaf(-2.f, a[1], p.y)),
                                    fminf(fmaf(-2.f, a[2], p.z), fmaf(-2.f, a[3], p.w)));
                    m[g][b][nt] = fminf(m[g][b][nt], v);
                }
            }
    }

    // ---- cross-lane min over q-groups, store from q==0 lanes ----
    #pragma unroll
    for (int g = 0; g < 2; g++)
        #pragma unroll
        for (int b = 0; b < NB; b++)
            #pragma unroll
            for (int nt = 0; nt < 2; nt++) {
                float v = m[g][b][nt];
                v = fminf(v, __shfl_xor(v, 16));
                v = fminf(v, __shfl_xor(v, 32));
                if (q == 0)
                    g_part[((g * NB + b) * NFB + fblk) * NP + nw + nt * 16 + c] = v;
            }
}

__global__ void finalize(float* __restrict__ out) {
    int idx = blockIdx.x * 256 + threadIdx.x;   // out layout (g*NB+b)*NN+n
    if (idx >= 2 * NB * NN) return;
    int sb = idx / NN;
    int n = idx % NN;
    float m = __builtin_inff();
    #pragma unroll 8
    for (int j = 0; j < NFB; j++) m = fminf(m, g_part[(sb * NFB + j) * NP + n]);
    float d2 = fmaxf(m + g_e2[n], 0.f);
    out[idx] = expf(-0.5f * d2);
}

extern "C" void kernel_launch(void* const* d_in, const int* in_sizes, int n_in,
                              void* d_out, int out_size, void* d_ws, size_t ws_size,
                              hipStream_t stream) {
    const float* rel  = (const float*)d_in[0];
    const float* arg1 = (const float*)d_in[1];
    const float* arg2 = (const float*)d_in[2];
    const float* frel = (const float*)d_in[3];
    const float* fa1  = (const float*)d_in[4];
    const float* fa2  = (const float*)d_in[5];
    const float* ent  = (const float*)d_in[6];
    float* out = (float*)d_out;

    prep<<<CVT_BLOCKS + E2_BLOCKS + P_BLOCKS, 256, 0, stream>>>(rel, arg1, arg2, frel, fa1, fa2, ent);
    main_kernel<<<dim3(NP / BN, NFB), 256, 0, stream>>>();
    finalize<<<(2 * NB * NN + 255) / 256, 256, 0, stream>>>(out);
}